// Round 1
// baseline (1190.170 us; speedup 1.0000x reference)
//
#include <hip/hip_runtime.h>

// GCN: 3x (linear -> symmetric-norm graph conv -> +bias -> tanh) -> linear
// N=200000 nodes, E=3200000 edges, F=256 -> 32 -> 16 -> 8 -> 4, all fp32.
// Round 1: correctness baseline. Scatter via global fp32 atomics.

constexpr int F_IN = 256;
constexpr int D1 = 32, D2 = 16, D3 = 8, D4 = 4;

// ---- degree ------------------------------------------------------------
__global__ void deg_kernel(const int* __restrict__ dst, float* __restrict__ deg, int E) {
    int e = blockIdx.x * blockDim.x + threadIdx.x;
    if (e < E) atomicAdd(&deg[dst[e]], 1.0f);
}

__global__ void rsqrt_kernel(const float* __restrict__ deg, float* __restrict__ dinv, int N) {
    int i = blockIdx.x * blockDim.x + threadIdx.x;
    if (i < N) dinv[i] = rsqrtf(deg[i] + 1.0f);
}

// ---- dense linear: out[N,D] = x[N,K] @ W[K,D] --------------------------
// 256 threads/block, R=256/D rows per block. W staged in LDS.
template <int K, int D>
__global__ void linear_kernel(const float* __restrict__ x, const float* __restrict__ W,
                              float* __restrict__ out, int N) {
    constexpr int R = 256 / D;
    __shared__ float Ws[K * D];
    for (int t = threadIdx.x; t < K * D; t += 256) Ws[t] = W[t];
    __syncthreads();
    const int c = threadIdx.x % D;
    const int r = threadIdx.x / D;
    const long row = (long)blockIdx.x * R + r;
    if (row >= N) return;
    const float* xr = x + row * K;
    float acc = 0.f;
#pragma unroll 8
    for (int k = 0; k < K; ++k) acc += xr[k] * Ws[k * D + c];
    out[row * D + c] = acc;
}

// ---- edge scatter: agg[dst] += h[src] * dinv[src]*dinv[dst] ------------
// one thread per (edge, channel); c fastest -> wave = 2 edges x 32 c,
// atomics land in 2 cache lines per wave (coalesced-ish).
template <int D>
__global__ void edge_scatter(const int* __restrict__ src, const int* __restrict__ dst,
                             const float* __restrict__ dinv, const float* __restrict__ h,
                             float* __restrict__ agg, long totalED) {
    long idx = (long)blockIdx.x * blockDim.x + threadIdx.x;
    if (idx >= totalED) return;
    int e = (int)(idx / D);
    int c = (int)(idx % D);
    int s = src[e], d = dst[e];
    float norm = dinv[s] * dinv[d];
    atomicAdd(&agg[(long)d * D + c], h[(long)s * D + c] * norm);
}

// ---- self-loop + bias + tanh (in place on agg) -------------------------
template <int D>
__global__ void finish_kernel(const float* __restrict__ hpre, const float* __restrict__ dinv,
                              const float* __restrict__ b, float* __restrict__ agg_h, long totalND) {
    long idx = (long)blockIdx.x * blockDim.x + threadIdx.x;
    if (idx >= totalND) return;
    int i = (int)(idx / D);
    int c = (int)(idx % D);
    float dv = dinv[i];
    float v = agg_h[idx] + hpre[idx] * dv * dv + b[c];
    agg_h[idx] = tanhf(v);
}

// ---- final classifier: out[N,4] = h[N,8] @ Wc[8,4] + bc ----------------
__global__ void final_kernel(const float* __restrict__ h, const float* __restrict__ Wc,
                             const float* __restrict__ bc, float* __restrict__ out, int N) {
    int i = blockIdx.x * blockDim.x + threadIdx.x;
    if (i >= N) return;
    float hr[8];
#pragma unroll
    for (int k = 0; k < 8; ++k) hr[k] = h[(long)i * 8 + k];
#pragma unroll
    for (int j = 0; j < 4; ++j) {
        float acc = bc[j];
#pragma unroll
        for (int k = 0; k < 8; ++k) acc += hr[k] * Wc[k * 4 + j];
        out[(long)i * 4 + j] = acc;
    }
}

extern "C" void kernel_launch(void* const* d_in, const int* in_sizes, int n_in,
                              void* d_out, int out_size, void* d_ws, size_t ws_size,
                              hipStream_t stream) {
    const float* x  = (const float*)d_in[0];
    const int*   ei = (const int*)d_in[1];
    const float* W1 = (const float*)d_in[2];
    const float* b1 = (const float*)d_in[3];
    const float* W2 = (const float*)d_in[4];
    const float* b2 = (const float*)d_in[5];
    const float* W3 = (const float*)d_in[6];
    const float* b3 = (const float*)d_in[7];
    const float* Wc = (const float*)d_in[8];
    const float* bc = (const float*)d_in[9];
    float* out = (float*)d_out;

    const int N = in_sizes[0] / F_IN;
    const int E = in_sizes[1] / 2;
    const int* src = ei;
    const int* dst = ei + E;

    float* ws   = (float*)d_ws;
    float* deg  = ws;                       // N
    float* dinv = ws + N;                   // N
    float* bufA = ws + 2 * (size_t)N;       // N*32 (hpre)
    float* bufB = bufA + (size_t)N * 32;    // N*32 (agg / h)

    const int B = 256;

    // degrees
    hipMemsetAsync(deg, 0, (size_t)N * sizeof(float), stream);
    deg_kernel<<<(E + B - 1) / B, B, 0, stream>>>(dst, deg, E);
    rsqrt_kernel<<<(N + B - 1) / B, B, 0, stream>>>(deg, dinv, N);

    // ---- layer 1: F_IN -> D1 ----
    linear_kernel<F_IN, D1><<<(N + (256 / D1) - 1) / (256 / D1), B, 0, stream>>>(x, W1, bufA, N);
    hipMemsetAsync(bufB, 0, (size_t)N * D1 * sizeof(float), stream);
    {
        long tot = (long)E * D1;
        edge_scatter<D1><<<(unsigned)((tot + B - 1) / B), B, 0, stream>>>(src, dst, dinv, bufA, bufB, tot);
        long nd = (long)N * D1;
        finish_kernel<D1><<<(unsigned)((nd + B - 1) / B), B, 0, stream>>>(bufA, dinv, b1, bufB, nd);
    }

    // ---- layer 2: D1 -> D2 ----
    linear_kernel<D1, D2><<<(N + (256 / D2) - 1) / (256 / D2), B, 0, stream>>>(bufB, W2, bufA, N);
    hipMemsetAsync(bufB, 0, (size_t)N * D2 * sizeof(float), stream);
    {
        long tot = (long)E * D2;
        edge_scatter<D2><<<(unsigned)((tot + B - 1) / B), B, 0, stream>>>(src, dst, dinv, bufA, bufB, tot);
        long nd = (long)N * D2;
        finish_kernel<D2><<<(unsigned)((nd + B - 1) / B), B, 0, stream>>>(bufA, dinv, b2, bufB, nd);
    }

    // ---- layer 3: D2 -> D3 ----
    linear_kernel<D2, D3><<<(N + (256 / D3) - 1) / (256 / D3), B, 0, stream>>>(bufB, W3, bufA, N);
    hipMemsetAsync(bufB, 0, (size_t)N * D3 * sizeof(float), stream);
    {
        long tot = (long)E * D3;
        edge_scatter<D3><<<(unsigned)((tot + B - 1) / B), B, 0, stream>>>(src, dst, dinv, bufA, bufB, tot);
        long nd = (long)N * D3;
        finish_kernel<D3><<<(unsigned)((nd + B - 1) / B), B, 0, stream>>>(bufA, dinv, b3, bufB, nd);
    }

    // ---- classifier: D3 -> D4 ----
    final_kernel<<<(N + B - 1) / B, B, 0, stream>>>(bufB, Wc, bc, out, N);
}

// Round 2
// 932.787 us; speedup vs baseline: 1.2759x; 1.2759x over previous
//
#include <hip/hip_runtime.h>

// GCN: 3x (linear -> symmetric-norm conv -> bias -> tanh) -> linear.
// N=200000, E=3200000, F=256->32->16->8->4, fp32.
// Round 2: CSR-by-dst gather (no fp32 atomics in hot loops) + tiled GEMM1.
// Algebra: norm = dinv[s]*dinv[d]  =>  agg_i = dinv_i * (hs_i + sum_in hs_src)
// with hs = (h @ W) * dinv computed in the linear epilogue.

constexpr int F_IN = 256;

// ---------------- CSR build ----------------
__global__ void hist_kernel(const int* __restrict__ dst, int* __restrict__ cnt, int E) {
    int e = blockIdx.x * blockDim.x + threadIdx.x;
    if (e < E) atomicAdd(&cnt[dst[e]], 1);
}

__global__ void dinv_kernel(const int* __restrict__ cnt, float* __restrict__ dinv, int N) {
    int i = blockIdx.x * blockDim.x + threadIdx.x;
    if (i < N) dinv[i] = rsqrtf((float)cnt[i] + 1.0f);
}

// exclusive scan of cnt -> rowptr; 1024 elements per block
__global__ void scan1_kernel(const int* __restrict__ cnt, int* __restrict__ rowptr,
                             int* __restrict__ bsum, int N) {
    __shared__ int s[256];
    const int t = threadIdx.x;
    const int base = blockIdx.x * 1024 + t * 4;
    int v[4]; int tot = 0;
#pragma unroll
    for (int i = 0; i < 4; ++i) { v[i] = (base + i < N) ? cnt[base + i] : 0; tot += v[i]; }
    s[t] = tot; __syncthreads();
    for (int off = 1; off < 256; off <<= 1) {
        int add = (t >= off) ? s[t - off] : 0; __syncthreads();
        s[t] += add; __syncthreads();
    }
    int pos = s[t] - tot;           // exclusive offset of this thread within block
#pragma unroll
    for (int i = 0; i < 4; ++i) { if (base + i < N) rowptr[base + i] = pos; pos += v[i]; }
    if (t == 255) bsum[blockIdx.x] = s[255];
}

// single-block exclusive scan of bsum (up to 1024 entries)
__global__ void scan2_kernel(int* __restrict__ bsum, int nb) {
    __shared__ int s[256];
    const int t = threadIdx.x;
    int v[4]; int tot = 0;
#pragma unroll
    for (int i = 0; i < 4; ++i) { int idx = t * 4 + i; v[i] = (idx < nb) ? bsum[idx] : 0; tot += v[i]; }
    s[t] = tot; __syncthreads();
    for (int off = 1; off < 256; off <<= 1) {
        int add = (t >= off) ? s[t - off] : 0; __syncthreads();
        s[t] += add; __syncthreads();
    }
    int pos = s[t] - tot;
#pragma unroll
    for (int i = 0; i < 4; ++i) { int idx = t * 4 + i; if (idx < nb) bsum[idx] = pos; pos += v[i]; }
}

__global__ void scan3_kernel(int* __restrict__ rowptr, const int* __restrict__ bsum, int N) {
    int i = blockIdx.x * blockDim.x + threadIdx.x;
    if (i < N) rowptr[i] += bsum[i >> 10];
}

__global__ void fill_kernel(const int* __restrict__ src, const int* __restrict__ dst,
                            const int* __restrict__ rowptr, int* __restrict__ cursor,
                            int* __restrict__ list, int E) {
    int e = blockIdx.x * blockDim.x + threadIdx.x;
    if (e >= E) return;
    int d = dst[e];
    int pos = rowptr[d] + atomicAdd(&cursor[d], 1);
    list[pos] = src[e];
}

// ---------------- layer-1 GEMM: out = (x @ W) * dinv, K=256, D=32 ----------------
// 256-row x 32-col tile per block; W (32KB) + 16-wide K-chunk of x in LDS;
// 4x8 register outer product per thread -> FMA-bound.
__global__ __launch_bounds__(256) void linear1_kernel(const float* __restrict__ x,
                                                      const float* __restrict__ W,
                                                      const float* __restrict__ dinv,
                                                      float* __restrict__ out, int N) {
    __shared__ float Ws[F_IN * 32];      // 32 KB
    __shared__ float xs[256][17];        // 256 rows x 16 k (+1 pad) = 17 KB
    const int t = threadIdx.x;
    for (int i = t; i < F_IN * 32 / 4; i += 256)
        ((float4*)Ws)[i] = ((const float4*)W)[i];
    const int rg = t >> 2;               // 0..63 : row group (4 rows)
    const int cg = t & 3;                // 0..3  : col group (8 cols)
    const long row0 = (long)blockIdx.x * 256;
    float acc[4][8] = {};
    for (int kc = 0; kc < 16; ++kc) {
        // stage x[row0..row0+255][kc*16 .. +16]
        for (int s = t; s < 1024; s += 256) {
            int r = s >> 2, k4 = (s & 3) * 4;
            long grow = row0 + r;
            float4 xv = make_float4(0.f, 0.f, 0.f, 0.f);
            if (grow < N) xv = *(const float4*)(x + grow * F_IN + kc * 16 + k4);
            *(float4*)&xs[r][k4] = xv;
        }
        __syncthreads();
#pragma unroll
        for (int kk = 0; kk < 16; ++kk) {
            float xv[4];
#pragma unroll
            for (int i = 0; i < 4; ++i) xv[i] = xs[rg * 4 + i][kk];
            const float4 w0 = *(const float4*)&Ws[(kc * 16 + kk) * 32 + cg * 8];
            const float4 w1 = *(const float4*)&Ws[(kc * 16 + kk) * 32 + cg * 8 + 4];
#pragma unroll
            for (int i = 0; i < 4; ++i) {
                acc[i][0] += xv[i] * w0.x; acc[i][1] += xv[i] * w0.y;
                acc[i][2] += xv[i] * w0.z; acc[i][3] += xv[i] * w0.w;
                acc[i][4] += xv[i] * w1.x; acc[i][5] += xv[i] * w1.y;
                acc[i][6] += xv[i] * w1.z; acc[i][7] += xv[i] * w1.w;
            }
        }
        __syncthreads();
    }
#pragma unroll
    for (int i = 0; i < 4; ++i) {
        long r = row0 + rg * 4 + i;
        if (r >= N) continue;
        float dv = dinv ? dinv[r] : 1.0f;
        float4 o0 = make_float4(acc[i][0] * dv, acc[i][1] * dv, acc[i][2] * dv, acc[i][3] * dv);
        float4 o1 = make_float4(acc[i][4] * dv, acc[i][5] * dv, acc[i][6] * dv, acc[i][7] * dv);
        *(float4*)(out + r * 32 + cg * 8) = o0;
        *(float4*)(out + r * 32 + cg * 8 + 4) = o1;
    }
}

// ---------------- small linear: out = (x @ W) * dinv, thread per row ----------------
template <int K, int D>
__global__ void linear_small_kernel(const float* __restrict__ x, const float* __restrict__ W,
                                    const float* __restrict__ dinv, float* __restrict__ out, int N) {
    __shared__ float Ws[K * D];
    const int t = threadIdx.x;
    for (int i = t; i < K * D; i += 256) Ws[i] = W[i];
    __syncthreads();
    long row = (long)blockIdx.x * 256 + t;
    if (row >= N) return;
    float acc[D] = {};
    const float4* xr = (const float4*)(x + row * K);
#pragma unroll
    for (int k4 = 0; k4 < K / 4; ++k4) {
        float4 xv = xr[k4];
        float xvs[4] = {xv.x, xv.y, xv.z, xv.w};
#pragma unroll
        for (int j = 0; j < 4; ++j) {
#pragma unroll
            for (int c4 = 0; c4 < D / 4; ++c4) {
                float4 w = *(const float4*)&Ws[(k4 * 4 + j) * D + c4 * 4];
                acc[c4 * 4 + 0] += xvs[j] * w.x;
                acc[c4 * 4 + 1] += xvs[j] * w.y;
                acc[c4 * 4 + 2] += xvs[j] * w.z;
                acc[c4 * 4 + 3] += xvs[j] * w.w;
            }
        }
    }
    float dv = dinv ? dinv[row] : 1.0f;
#pragma unroll
    for (int c4 = 0; c4 < D / 4; ++c4) {
        float4 o = make_float4(acc[c4 * 4 + 0] * dv, acc[c4 * 4 + 1] * dv,
                               acc[c4 * 4 + 2] * dv, acc[c4 * 4 + 3] * dv);
        *(float4*)(out + row * D + c4 * 4) = o;
    }
}

// ---------------- gather aggregate: out_i = tanh(dinv_i*(hs_i + sum hs_src) + b) ----------------
template <int D>
__global__ void gather_kernel(const int* __restrict__ rowptr, const int* __restrict__ cnt,
                              const int* __restrict__ list, const float* __restrict__ hs,
                              const float* __restrict__ dinv, const float* __restrict__ b,
                              float* __restrict__ out, int N) {
    constexpr int GPB = 256 / D;
    const int g = threadIdx.x / D, c = threadIdx.x % D;
    long node = (long)blockIdx.x * GPB + g;
    if (node >= N) return;
    const int start = rowptr[node];
    const int num = cnt[node];
    float acc = hs[node * D + c];            // self-loop term
    for (int j = 0; j < num; ++j) {
        int s = list[start + j];             // broadcast within node group
        acc += hs[(long)s * D + c];          // 128B-coalesced per group
    }
    out[node * D + c] = tanhf(dinv[node] * acc + b[c]);
}

// ---------------- final classifier ----------------
__global__ void final_kernel(const float* __restrict__ h, const float* __restrict__ Wc,
                             const float* __restrict__ bc, float* __restrict__ out, int N) {
    int i = blockIdx.x * blockDim.x + threadIdx.x;
    if (i >= N) return;
    float hr[8];
#pragma unroll
    for (int k = 0; k < 8; ++k) hr[k] = h[(long)i * 8 + k];
#pragma unroll
    for (int j = 0; j < 4; ++j) {
        float acc = bc[j];
#pragma unroll
        for (int k = 0; k < 8; ++k) acc += hr[k] * Wc[k * 4 + j];
        out[(long)i * 4 + j] = acc;
    }
}

// ---------------- fallback (atomic scatter) kernels, kept from round 1 ----------------
template <int D>
__global__ void edge_scatter(const int* __restrict__ src, const int* __restrict__ dst,
                             const float* __restrict__ dinv, const float* __restrict__ h,
                             float* __restrict__ agg, long totalED) {
    long idx = (long)blockIdx.x * blockDim.x + threadIdx.x;
    if (idx >= totalED) return;
    int e = (int)(idx / D);
    int c = (int)(idx % D);
    int s = src[e], d = dst[e];
    float norm = dinv[s] * dinv[d];
    atomicAdd(&agg[(long)d * D + c], h[(long)s * D + c] * norm);
}

template <int D>
__global__ void finish_kernel(const float* __restrict__ hpre, const float* __restrict__ dinv,
                              const float* __restrict__ b, float* __restrict__ agg_h, long totalND) {
    long idx = (long)blockIdx.x * blockDim.x + threadIdx.x;
    if (idx >= totalND) return;
    int i = (int)(idx / D);
    int c = (int)(idx % D);
    float dv = dinv[i];
    float v = agg_h[idx] + hpre[idx] * dv * dv + b[c];
    agg_h[idx] = tanhf(v);
}

extern "C" void kernel_launch(void* const* d_in, const int* in_sizes, int n_in,
                              void* d_out, int out_size, void* d_ws, size_t ws_size,
                              hipStream_t stream) {
    const float* x  = (const float*)d_in[0];
    const int*   ei = (const int*)d_in[1];
    const float* W1 = (const float*)d_in[2];
    const float* b1 = (const float*)d_in[3];
    const float* W2 = (const float*)d_in[4];
    const float* b2 = (const float*)d_in[5];
    const float* W3 = (const float*)d_in[6];
    const float* b3 = (const float*)d_in[7];
    const float* Wc = (const float*)d_in[8];
    const float* bc = (const float*)d_in[9];
    float* out = (float*)d_out;

    const int N = in_sizes[0] / F_IN;
    const int E = in_sizes[1] / 2;
    const int* src = ei;
    const int* dst = ei + E;
    const int B = 256;

    // workspace layout (16B-aligned chunks)
    char* p = (char*)d_ws;
    auto take = [&](size_t bytes) { char* q = p; p += (bytes + 255) & ~size_t(255); return q; };
    int*   cnt    = (int*)take((size_t)N * 4);         // counts, then cursor, then counts again
    int*   rowptr = (int*)take((size_t)N * 4);
    int*   bsum   = (int*)take(1024 * 4);
    float* dinv   = (float*)take((size_t)N * 4);
    int*   list   = (int*)take((size_t)E * 4);
    float* bufA   = (float*)take((size_t)N * 32 * 4);
    float* bufB   = (float*)take((size_t)N * 32 * 4);
    const size_t needed = (size_t)(p - (char*)d_ws);
    const bool use_csr = needed <= ws_size;

    const int nb1024 = (N + 1023) / 1024;

    if (use_csr) {
        // ---- CSR by dst ----
        hipMemsetAsync(cnt, 0, (size_t)N * 4, stream);
        hist_kernel<<<(E + B - 1) / B, B, 0, stream>>>(dst, cnt, E);
        dinv_kernel<<<(N + B - 1) / B, B, 0, stream>>>(cnt, dinv, N);
        scan1_kernel<<<nb1024, B, 0, stream>>>(cnt, rowptr, bsum, N);
        scan2_kernel<<<1, B, 0, stream>>>(bsum, nb1024);
        scan3_kernel<<<(N + B - 1) / B, B, 0, stream>>>(rowptr, bsum, N);
        hipMemsetAsync(cnt, 0, (size_t)N * 4, stream);   // cursor; ends == counts again
        fill_kernel<<<(E + B - 1) / B, B, 0, stream>>>(src, dst, rowptr, cnt, list, E);

        // ---- layer 1 ----
        linear1_kernel<<<(N + 255) / 256, B, 0, stream>>>(x, W1, dinv, bufA, N);
        gather_kernel<32><<<(N + 7) / 8, B, 0, stream>>>(rowptr, cnt, list, bufA, dinv, b1, bufB, N);
        // ---- layer 2 ----
        linear_small_kernel<32, 16><<<(N + 255) / 256, B, 0, stream>>>(bufB, W2, dinv, bufA, N);
        gather_kernel<16><<<(N + 15) / 16, B, 0, stream>>>(rowptr, cnt, list, bufA, dinv, b2, bufB, N);
        // ---- layer 3 ----
        linear_small_kernel<16, 8><<<(N + 255) / 256, B, 0, stream>>>(bufB, W3, dinv, bufA, N);
        gather_kernel<8><<<(N + 31) / 32, B, 0, stream>>>(rowptr, cnt, list, bufA, dinv, b3, bufB, N);
        // ---- classifier ----
        final_kernel<<<(N + B - 1) / B, B, 0, stream>>>(bufB, Wc, bc, out, N);
    } else {
        // fallback: atomic scatter path (fits in the round-1 footprint)
        char* q = (char*)d_ws;
        auto take2 = [&](size_t bytes) { char* r = q; q += (bytes + 255) & ~size_t(255); return r; };
        int*   cnt2  = (int*)take2((size_t)N * 4);
        float* dinv2 = (float*)take2((size_t)N * 4);
        float* bA    = (float*)take2((size_t)N * 32 * 4);
        float* bB    = (float*)take2((size_t)N * 32 * 4);

        hipMemsetAsync(cnt2, 0, (size_t)N * 4, stream);
        hist_kernel<<<(E + B - 1) / B, B, 0, stream>>>(dst, cnt2, E);
        dinv_kernel<<<(N + B - 1) / B, B, 0, stream>>>(cnt2, dinv2, N);

        linear1_kernel<<<(N + 255) / 256, B, 0, stream>>>(x, W1, nullptr, bA, N);
        hipMemsetAsync(bB, 0, (size_t)N * 32 * 4, stream);
        edge_scatter<32><<<(unsigned)(((long)E * 32 + B - 1) / B), B, 0, stream>>>(src, dst, dinv2, bA, bB, (long)E * 32);
        finish_kernel<32><<<(unsigned)(((long)N * 32 + B - 1) / B), B, 0, stream>>>(bA, dinv2, b1, bB, (long)N * 32);

        linear_small_kernel<32, 16><<<(N + 255) / 256, B, 0, stream>>>(bB, W2, nullptr, bA, N);
        hipMemsetAsync(bB, 0, (size_t)N * 16 * 4, stream);
        edge_scatter<16><<<(unsigned)(((long)E * 16 + B - 1) / B), B, 0, stream>>>(src, dst, dinv2, bA, bB, (long)E * 16);
        finish_kernel<16><<<(unsigned)(((long)N * 16 + B - 1) / B), B, 0, stream>>>(bA, dinv2, b2, bB, (long)N * 16);

        linear_small_kernel<16, 8><<<(N + 255) / 256, B, 0, stream>>>(bB, W3, nullptr, bA, N);
        hipMemsetAsync(bB, 0, (size_t)N * 8 * 4, stream);
        edge_scatter<8><<<(unsigned)(((long)E * 8 + B - 1) / B), B, 0, stream>>>(src, dst, dinv2, bA, bB, (long)E * 8);
        finish_kernel<8><<<(unsigned)(((long)N * 8 + B - 1) / B), B, 0, stream>>>(bA, dinv2, b3, bB, (long)N * 8);

        final_kernel<<<(N + B - 1) / B, B, 0, stream>>>(bB, Wc, bc, out, N);
    }
}

// Round 3
// 580.291 us; speedup vs baseline: 2.0510x; 1.6074x over previous
//
#include <hip/hip_runtime.h>

// GCN: 3x (linear -> symmetric-norm conv -> bias -> tanh) -> linear.
// N=200000, E=3200000, F=256->32->16->8->4, fp32.
// Round 3: gather with float4 lanes + 8-deep edge unroll (MLP for latency
// hiding); classifier fused into the D=8 gather via pair shfl-reduce.
// Algebra: norm = dinv[s]*dinv[d]  =>  agg_i = dinv_i * (hs_i + sum_in hs_src)
// with hs = (h @ W) * dinv computed in each linear's epilogue.

constexpr int F_IN = 256;

// ---------------- CSR build ----------------
__global__ void hist_kernel(const int* __restrict__ dst, int* __restrict__ cnt, int E) {
    int e = blockIdx.x * blockDim.x + threadIdx.x;
    if (e < E) atomicAdd(&cnt[dst[e]], 1);
}

__global__ void dinv_kernel(const int* __restrict__ cnt, float* __restrict__ dinv, int N) {
    int i = blockIdx.x * blockDim.x + threadIdx.x;
    if (i < N) dinv[i] = rsqrtf((float)cnt[i] + 1.0f);
}

// exclusive scan of cnt -> rowptr; 1024 elements per block
__global__ void scan1_kernel(const int* __restrict__ cnt, int* __restrict__ rowptr,
                             int* __restrict__ bsum, int N) {
    __shared__ int s[256];
    const int t = threadIdx.x;
    const int base = blockIdx.x * 1024 + t * 4;
    int v[4]; int tot = 0;
#pragma unroll
    for (int i = 0; i < 4; ++i) { v[i] = (base + i < N) ? cnt[base + i] : 0; tot += v[i]; }
    s[t] = tot; __syncthreads();
    for (int off = 1; off < 256; off <<= 1) {
        int add = (t >= off) ? s[t - off] : 0; __syncthreads();
        s[t] += add; __syncthreads();
    }
    int pos = s[t] - tot;
#pragma unroll
    for (int i = 0; i < 4; ++i) { if (base + i < N) rowptr[base + i] = pos; pos += v[i]; }
    if (t == 255) bsum[blockIdx.x] = s[255];
}

__global__ void scan2_kernel(int* __restrict__ bsum, int nb) {
    __shared__ int s[256];
    const int t = threadIdx.x;
    int v[4]; int tot = 0;
#pragma unroll
    for (int i = 0; i < 4; ++i) { int idx = t * 4 + i; v[i] = (idx < nb) ? bsum[idx] : 0; tot += v[i]; }
    s[t] = tot; __syncthreads();
    for (int off = 1; off < 256; off <<= 1) {
        int add = (t >= off) ? s[t - off] : 0; __syncthreads();
        s[t] += add; __syncthreads();
    }
    int pos = s[t] - tot;
#pragma unroll
    for (int i = 0; i < 4; ++i) { int idx = t * 4 + i; if (idx < nb) bsum[idx] = pos; pos += v[i]; }
}

__global__ void scan3_kernel(int* __restrict__ rowptr, const int* __restrict__ bsum, int N) {
    int i = blockIdx.x * blockDim.x + threadIdx.x;
    if (i < N) rowptr[i] += bsum[i >> 10];
}

__global__ void fill_kernel(const int* __restrict__ src, const int* __restrict__ dst,
                            const int* __restrict__ rowptr, int* __restrict__ cursor,
                            int* __restrict__ list, int E) {
    int e = blockIdx.x * blockDim.x + threadIdx.x;
    if (e >= E) return;
    int d = dst[e];
    int pos = rowptr[d] + atomicAdd(&cursor[d], 1);
    list[pos] = src[e];
}

// ---------------- layer-1 GEMM: out = (x @ W) * dinv, K=256, D=32 ----------------
__global__ __launch_bounds__(256) void linear1_kernel(const float* __restrict__ x,
                                                      const float* __restrict__ W,
                                                      const float* __restrict__ dinv,
                                                      float* __restrict__ out, int N) {
    __shared__ float Ws[F_IN * 32];      // 32 KB
    __shared__ float xs[256][17];        // 17 KB
    const int t = threadIdx.x;
    for (int i = t; i < F_IN * 32 / 4; i += 256)
        ((float4*)Ws)[i] = ((const float4*)W)[i];
    const int rg = t >> 2;               // 0..63 : row group (4 rows)
    const int cg = t & 3;                // 0..3  : col group (8 cols)
    const long row0 = (long)blockIdx.x * 256;
    float acc[4][8] = {};
    for (int kc = 0; kc < 16; ++kc) {
        for (int s = t; s < 1024; s += 256) {
            int r = s >> 2, k4 = (s & 3) * 4;
            long grow = row0 + r;
            float4 xv = make_float4(0.f, 0.f, 0.f, 0.f);
            if (grow < N) xv = *(const float4*)(x + grow * F_IN + kc * 16 + k4);
            *(float4*)&xs[r][k4] = xv;
        }
        __syncthreads();
#pragma unroll
        for (int kk = 0; kk < 16; ++kk) {
            float xv[4];
#pragma unroll
            for (int i = 0; i < 4; ++i) xv[i] = xs[rg * 4 + i][kk];
            const float4 w0 = *(const float4*)&Ws[(kc * 16 + kk) * 32 + cg * 8];
            const float4 w1 = *(const float4*)&Ws[(kc * 16 + kk) * 32 + cg * 8 + 4];
#pragma unroll
            for (int i = 0; i < 4; ++i) {
                acc[i][0] += xv[i] * w0.x; acc[i][1] += xv[i] * w0.y;
                acc[i][2] += xv[i] * w0.z; acc[i][3] += xv[i] * w0.w;
                acc[i][4] += xv[i] * w1.x; acc[i][5] += xv[i] * w1.y;
                acc[i][6] += xv[i] * w1.z; acc[i][7] += xv[i] * w1.w;
            }
        }
        __syncthreads();
    }
#pragma unroll
    for (int i = 0; i < 4; ++i) {
        long r = row0 + rg * 4 + i;
        if (r >= N) continue;
        float dv = dinv[r];
        float4 o0 = make_float4(acc[i][0] * dv, acc[i][1] * dv, acc[i][2] * dv, acc[i][3] * dv);
        float4 o1 = make_float4(acc[i][4] * dv, acc[i][5] * dv, acc[i][6] * dv, acc[i][7] * dv);
        *(float4*)(out + r * 32 + cg * 8) = o0;
        *(float4*)(out + r * 32 + cg * 8 + 4) = o1;
    }
}

// ---------------- small linear: out = (x @ W) * dinv, thread per row ----------------
template <int K, int D>
__global__ void linear_small_kernel(const float* __restrict__ x, const float* __restrict__ W,
                                    const float* __restrict__ dinv, float* __restrict__ out, int N) {
    __shared__ float Ws[K * D];
    const int t = threadIdx.x;
    for (int i = t; i < K * D; i += 256) Ws[i] = W[i];
    __syncthreads();
    long row = (long)blockIdx.x * 256 + t;
    if (row >= N) return;
    float acc[D] = {};
    const float4* xr = (const float4*)(x + row * K);
#pragma unroll
    for (int k4 = 0; k4 < K / 4; ++k4) {
        float4 xv = xr[k4];
        float xvs[4] = {xv.x, xv.y, xv.z, xv.w};
#pragma unroll
        for (int j = 0; j < 4; ++j) {
#pragma unroll
            for (int c4 = 0; c4 < D / 4; ++c4) {
                float4 w = *(const float4*)&Ws[(k4 * 4 + j) * D + c4 * 4];
                acc[c4 * 4 + 0] += xvs[j] * w.x;
                acc[c4 * 4 + 1] += xvs[j] * w.y;
                acc[c4 * 4 + 2] += xvs[j] * w.z;
                acc[c4 * 4 + 3] += xvs[j] * w.w;
            }
        }
    }
    float dv = dinv[row];
#pragma unroll
    for (int c4 = 0; c4 < D / 4; ++c4) {
        float4 o = make_float4(acc[c4 * 4 + 0] * dv, acc[c4 * 4 + 1] * dv,
                               acc[c4 * 4 + 2] * dv, acc[c4 * 4 + 3] * dv);
        *(float4*)(out + row * D + c4 * 4) = o;
    }
}

// ---------------- gather: out_i = tanh(dinv_i*(hs_i + sum hs_src) + b) ----------------
// L = D/4 lanes per node, each lane owns a float4 of channels. 8-deep edge
// unroll -> 8 outstanding 128B gathers per node group (latency hiding).
template <int D>
__global__ void gather_kernel(const int* __restrict__ rowptr, const int* __restrict__ cnt,
                              const int* __restrict__ list, const float* __restrict__ hs,
                              const float* __restrict__ dinv, const float* __restrict__ b,
                              float* __restrict__ out, int N) {
    constexpr int L = D / 4;
    constexpr int GPB = 256 / L;
    const int t = threadIdx.x;
    const int g = t / L, lane = t % L;
    long node = (long)blockIdx.x * GPB + g;
    if (node >= N) return;
    const int start = rowptr[node];
    const int num = cnt[node];
    const int* __restrict__ lp = list + start;
    const float4* __restrict__ hs4 = (const float4*)hs;
    float4 acc = hs4[node * L + lane];
    int j = 0;
    for (; j + 8 <= num; j += 8) {
        int s0 = lp[j], s1 = lp[j + 1], s2 = lp[j + 2], s3 = lp[j + 3];
        int s4 = lp[j + 4], s5 = lp[j + 5], s6 = lp[j + 6], s7 = lp[j + 7];
        float4 v0 = hs4[(long)s0 * L + lane], v1 = hs4[(long)s1 * L + lane];
        float4 v2 = hs4[(long)s2 * L + lane], v3 = hs4[(long)s3 * L + lane];
        float4 v4 = hs4[(long)s4 * L + lane], v5 = hs4[(long)s5 * L + lane];
        float4 v6 = hs4[(long)s6 * L + lane], v7 = hs4[(long)s7 * L + lane];
        acc.x += ((v0.x + v1.x) + (v2.x + v3.x)) + ((v4.x + v5.x) + (v6.x + v7.x));
        acc.y += ((v0.y + v1.y) + (v2.y + v3.y)) + ((v4.y + v5.y) + (v6.y + v7.y));
        acc.z += ((v0.z + v1.z) + (v2.z + v3.z)) + ((v4.z + v5.z) + (v6.z + v7.z));
        acc.w += ((v0.w + v1.w) + (v2.w + v3.w)) + ((v4.w + v5.w) + (v6.w + v7.w));
    }
    for (; j < num; ++j) {
        int s = lp[j];
        float4 v = hs4[(long)s * L + lane];
        acc.x += v.x; acc.y += v.y; acc.z += v.z; acc.w += v.w;
    }
    const float dv = dinv[node];
    const float4 bb = *(const float4*)(b + lane * 4);
    float4 o;
    o.x = tanhf(acc.x * dv + bb.x);
    o.y = tanhf(acc.y * dv + bb.y);
    o.z = tanhf(acc.z * dv + bb.z);
    o.w = tanhf(acc.w * dv + bb.w);
    *(float4*)(out + node * D + lane * 4) = o;
}

// ---------------- D=8 gather fused with classifier: out = h3 @ Wc + bc ----------------
// 2 lanes per node (float4 each). After tanh, each lane computes its partial
// of the 8x4 matvec; pair shfl_xor(1) reduce; lane 0 writes float4.
__global__ void gather8_final_kernel(const int* __restrict__ rowptr, const int* __restrict__ cnt,
                                     const int* __restrict__ list, const float* __restrict__ hs,
                                     const float* __restrict__ dinv, const float* __restrict__ b,
                                     const float* __restrict__ Wc, const float* __restrict__ bc,
                                     float* __restrict__ out, int N) {
    const int t = threadIdx.x;
    const int g = t >> 1, lane = t & 1;
    long node = (long)blockIdx.x * 128 + g;
    if (node >= N) return;
    const int start = rowptr[node];
    const int num = cnt[node];
    const int* __restrict__ lp = list + start;
    const float4* __restrict__ hs4 = (const float4*)hs;
    float4 acc = hs4[node * 2 + lane];
    int j = 0;
    for (; j + 8 <= num; j += 8) {
        int s0 = lp[j], s1 = lp[j + 1], s2 = lp[j + 2], s3 = lp[j + 3];
        int s4 = lp[j + 4], s5 = lp[j + 5], s6 = lp[j + 6], s7 = lp[j + 7];
        float4 v0 = hs4[(long)s0 * 2 + lane], v1 = hs4[(long)s1 * 2 + lane];
        float4 v2 = hs4[(long)s2 * 2 + lane], v3 = hs4[(long)s3 * 2 + lane];
        float4 v4 = hs4[(long)s4 * 2 + lane], v5 = hs4[(long)s5 * 2 + lane];
        float4 v6 = hs4[(long)s6 * 2 + lane], v7 = hs4[(long)s7 * 2 + lane];
        acc.x += ((v0.x + v1.x) + (v2.x + v3.x)) + ((v4.x + v5.x) + (v6.x + v7.x));
        acc.y += ((v0.y + v1.y) + (v2.y + v3.y)) + ((v4.y + v5.y) + (v6.y + v7.y));
        acc.z += ((v0.z + v1.z) + (v2.z + v3.z)) + ((v4.z + v5.z) + (v6.z + v7.z));
        acc.w += ((v0.w + v1.w) + (v2.w + v3.w)) + ((v4.w + v5.w) + (v6.w + v7.w));
    }
    for (; j < num; ++j) {
        int s = lp[j];
        float4 v = hs4[(long)s * 2 + lane];
        acc.x += v.x; acc.y += v.y; acc.z += v.z; acc.w += v.w;
    }
    const float dv = dinv[node];
    const float4 bb = *(const float4*)(b + lane * 4);
    float4 h;
    h.x = tanhf(acc.x * dv + bb.x);
    h.y = tanhf(acc.y * dv + bb.y);
    h.z = tanhf(acc.z * dv + bb.z);
    h.w = tanhf(acc.w * dv + bb.w);
    // partial matvec: rows lane*4 .. lane*4+3 of Wc[8][4]
    const float4 w0 = *(const float4*)(Wc + (lane * 4 + 0) * 4);
    const float4 w1 = *(const float4*)(Wc + (lane * 4 + 1) * 4);
    const float4 w2 = *(const float4*)(Wc + (lane * 4 + 2) * 4);
    const float4 w3 = *(const float4*)(Wc + (lane * 4 + 3) * 4);
    float4 p;
    p.x = h.x * w0.x + h.y * w1.x + h.z * w2.x + h.w * w3.x;
    p.y = h.x * w0.y + h.y * w1.y + h.z * w2.y + h.w * w3.y;
    p.z = h.x * w0.z + h.y * w1.z + h.z * w2.z + h.w * w3.z;
    p.w = h.x * w0.w + h.y * w1.w + h.z * w2.w + h.w * w3.w;
    p.x += __shfl_xor(p.x, 1);
    p.y += __shfl_xor(p.y, 1);
    p.z += __shfl_xor(p.z, 1);
    p.w += __shfl_xor(p.w, 1);
    if (lane == 0) {
        const float4 bcv = *(const float4*)bc;
        float4 o = make_float4(p.x + bcv.x, p.y + bcv.y, p.z + bcv.z, p.w + bcv.w);
        *(float4*)(out + node * 4) = o;
    }
}

extern "C" void kernel_launch(void* const* d_in, const int* in_sizes, int n_in,
                              void* d_out, int out_size, void* d_ws, size_t ws_size,
                              hipStream_t stream) {
    const float* x  = (const float*)d_in[0];
    const int*   ei = (const int*)d_in[1];
    const float* W1 = (const float*)d_in[2];
    const float* b1 = (const float*)d_in[3];
    const float* W2 = (const float*)d_in[4];
    const float* b2 = (const float*)d_in[5];
    const float* W3 = (const float*)d_in[6];
    const float* b3 = (const float*)d_in[7];
    const float* Wc = (const float*)d_in[8];
    const float* bc = (const float*)d_in[9];
    float* out = (float*)d_out;

    const int N = in_sizes[0] / F_IN;
    const int E = in_sizes[1] / 2;
    const int* src = ei;
    const int* dst = ei + E;
    const int B = 256;

    char* p = (char*)d_ws;
    auto take = [&](size_t bytes) { char* q = p; p += (bytes + 255) & ~size_t(255); return q; };
    int*   cnt    = (int*)take((size_t)N * 4);     // counts -> cursor -> counts
    int*   rowptr = (int*)take((size_t)N * 4);
    int*   bsum   = (int*)take(1024 * 4);
    float* dinv   = (float*)take((size_t)N * 4);
    int*   list   = (int*)take((size_t)E * 4);
    float* bufA   = (float*)take((size_t)N * 32 * 4);
    float* bufB   = (float*)take((size_t)N * 32 * 4);

    const int nb1024 = (N + 1023) / 1024;

    // ---- CSR by dst ----
    hipMemsetAsync(cnt, 0, (size_t)N * 4, stream);
    hist_kernel<<<(E + B - 1) / B, B, 0, stream>>>(dst, cnt, E);
    dinv_kernel<<<(N + B - 1) / B, B, 0, stream>>>(cnt, dinv, N);
    scan1_kernel<<<nb1024, B, 0, stream>>>(cnt, rowptr, bsum, N);
    scan2_kernel<<<1, B, 0, stream>>>(bsum, nb1024);
    scan3_kernel<<<(N + B - 1) / B, B, 0, stream>>>(rowptr, bsum, N);
    hipMemsetAsync(cnt, 0, (size_t)N * 4, stream);
    fill_kernel<<<(E + B - 1) / B, B, 0, stream>>>(src, dst, rowptr, cnt, list, E);

    // ---- layer 1: 256 -> 32 ----
    linear1_kernel<<<(N + 255) / 256, B, 0, stream>>>(x, W1, dinv, bufA, N);
    gather_kernel<32><<<(N + 31) / 32, B, 0, stream>>>(rowptr, cnt, list, bufA, dinv, b1, bufB, N);
    // ---- layer 2: 32 -> 16 ----
    linear_small_kernel<32, 16><<<(N + 255) / 256, B, 0, stream>>>(bufB, W2, dinv, bufA, N);
    gather_kernel<16><<<(N + 63) / 64, B, 0, stream>>>(rowptr, cnt, list, bufA, dinv, b2, bufB, N);
    // ---- layer 3: 16 -> 8, classifier fused ----
    linear_small_kernel<16, 8><<<(N + 255) / 256, B, 0, stream>>>(bufB, W3, dinv, bufA, N);
    gather8_final_kernel<<<(N + 127) / 128, B, 0, stream>>>(rowptr, cnt, list, bufA, dinv, b3, Wc, bc, out, N);
}